// Round 20
// baseline (176.868 us; speedup 1.0000x reference)
//
#include <hip/hip_runtime.h>
#include <hip/hip_bf16.h>
#include <stdint.h>

typedef __bf16 bf16_t;
typedef bf16_t bf16x8 __attribute__((ext_vector_type(8)));
typedef float  f32x4  __attribute__((ext_vector_type(4)));
typedef int    i32x4  __attribute__((ext_vector_type(4)));

#define M_TOK 2048
#define N_OUT 11008
#define K_IN  4096
#define N16   (N_OUT / 16)   // 688

// ---------- merged pre-pass: W repack (blocks 0..687) + X quant (688..2735) --
// W8t: B-frag (kt, n16) = 1 KB at ((kt*688 + n16)*64 + lane)*16.
// X8t: A-frag (kt, m16) = 1 KB at ((kt*128 + m16)*64 + lane)*16.
__global__ __launch_bounds__(256)
void prep(const int* __restrict__ Q, const float* __restrict__ X,
          signed char* __restrict__ W8t, signed char* __restrict__ X8t,
          float* __restrict__ dxv, float* __restrict__ sxv)
{
    __shared__ float wmax[4];
    __shared__ int   wsum[4];
    const int tid = threadIdx.x;

    if (blockIdx.x < N16) {
        const int n16 = blockIdx.x;
        const int fr  = tid & 15;
        const int fg  = (tid >> 4) & 3;
        const int w   = tid >> 6;
        const int* qrow = Q + (size_t)(n16 * 16 + fr) * K_IN + fg * 16;
        signed char* wout = W8t + ((size_t)n16 * 64 + (tid & 63)) * 16;
        #pragma unroll 4
        for (int kt2 = 0; kt2 < 16; ++kt2) {
            const int kt = kt2 * 4 + w;
            const int4* q4 = (const int4*)(qrow + kt * 64);
            unsigned int pk[4];
            #pragma unroll
            for (int j = 0; j < 4; ++j) {
                const int4 q = q4[j];
                pk[j] =  (unsigned int)((q.x - 128) & 255)
                      | ((unsigned int)((q.y - 128) & 255) << 8)
                      | ((unsigned int)((q.z - 128) & 255) << 16)
                      | ((unsigned int)((q.w - 128) & 255) << 24);
            }
            *(int4*)(wout + (size_t)kt * (N16 * 1024)) = *(const int4*)pk;
        }
        return;
    }

    const int row = blockIdx.x - N16;
    const float* xr = X + (size_t)row * K_IN + tid * 16;
    float v[16];
    #pragma unroll
    for (int j = 0; j < 4; ++j)
        *(float4*)(v + j * 4) = ((const float4*)xr)[j];

    float amax = 0.f;
    #pragma unroll
    for (int j = 0; j < 16; ++j) amax = fmaxf(amax, fabsf(v[j]));
    #pragma unroll
    for (int m = 1; m < 64; m <<= 1)
        amax = fmaxf(amax, __shfl_xor(amax, m));
    const int wv = tid >> 6;
    if ((tid & 63) == 0) wmax[wv] = amax;
    __syncthreads();
    amax = fmaxf(fmaxf(wmax[0], wmax[1]), fmaxf(wmax[2], wmax[3]));
    amax = fmaxf(amax, 1e-20f);
    const float inv = 127.f / amax;

    int sum = 0;
    unsigned int pk[4];
    #pragma unroll
    for (int j = 0; j < 4; ++j) {
        unsigned int p = 0;
        #pragma unroll
        for (int i = 0; i < 4; ++i) {
            int xi = (int)__builtin_rintf(v[j * 4 + i] * inv);
            xi = max(-127, min(127, xi));
            sum += xi;
            p |= ((unsigned int)(xi & 255)) << (8 * i);
        }
        pk[j] = p;
    }
    const size_t toff = (((size_t)(tid >> 2) * 128 + (row >> 4)) * 64
                         + (size_t)((tid & 3) * 16 + (row & 15))) * 16;
    *(int4*)(X8t + toff) = *(const int4*)pk;

    #pragma unroll
    for (int m = 1; m < 64; m <<= 1) sum += __shfl_xor(sum, m);
    if ((tid & 63) == 0) wsum[wv] = sum;
    __syncthreads();
    if (tid == 0) {
        dxv[row] = amax * (1.f / 127.f);
        sxv[row] = (float)(wsum[0] + wsum[1] + wsum[2] + wsum[3]);
    }
}

// ---------------- main GEMM: i8 128x256, NO LDS/barriers, depth-2 B prefetch -
// r19 body (best: 114us, VGPR 124, absmax 8.0) wrapped in a static 1-or-2-tile
// loop. Grid 512 = exactly 2 blocks/CU. Per XCD (86 tiles, 64 blocks):
// j<42 -> 1 tile (k=j); j>=42 -> 2 tiles (k=42+2(j-42), +1) — all in the same
// XCD col-partition (locality preserved; bijective over 86x8). Removes the
// 176-block second dispatch round: a 2-tile block starts tile 2 immediately
// when tile 1 ends, so the tail overlaps instead of serializing.
// setprio kept (r13 A/B: -22% without).

#define LOAD_A4(DA, KT) do {                                                   \
    const char* ap_ = gAt + (size_t)(KT) * (128 * 1024);                       \
    DA##0 = *(const i32x4*)(ap_ + 0 * 1024);                                   \
    DA##1 = *(const i32x4*)(ap_ + 1 * 1024);                                   \
    DA##2 = *(const i32x4*)(ap_ + 2 * 1024);                                   \
    DA##3 = *(const i32x4*)(ap_ + 3 * 1024);                                   \
} while (0)

#define LOAD_BH(BS, H) do {                                                    \
    const char* bp_ = gBt + (size_t)((H) >> 1) * (N16 * 1024)                  \
                          + (size_t)((H) & 1) * 4096;                          \
    BS##0 = *(const i32x4*)(bp_ + 0 * 1024);                                   \
    BS##1 = *(const i32x4*)(bp_ + 1 * 1024);                                   \
    BS##2 = *(const i32x4*)(bp_ + 2 * 1024);                                   \
    BS##3 = *(const i32x4*)(bp_ + 3 * 1024);                                   \
} while (0)

#define MMH(FA, BS, MQ, NH, NQ)                                                \
    acc[MQ][(NH) * 4 + (NQ)] = __builtin_amdgcn_mfma_i32_16x16x64_i8(          \
        FA##MQ, BS##NQ, acc[MQ][(NH) * 4 + (NQ)], 0, 0, 0)

#define MFMA16H(FA, BS, NH) do {                                               \
    __builtin_amdgcn_s_setprio(1);                                             \
    MMH(FA, BS, 0, NH, 0); MMH(FA, BS, 0, NH, 1);                              \
    MMH(FA, BS, 0, NH, 2); MMH(FA, BS, 0, NH, 3);                              \
    MMH(FA, BS, 1, NH, 0); MMH(FA, BS, 1, NH, 1);                              \
    MMH(FA, BS, 1, NH, 2); MMH(FA, BS, 1, NH, 3);                              \
    MMH(FA, BS, 2, NH, 0); MMH(FA, BS, 2, NH, 1);                              \
    MMH(FA, BS, 2, NH, 2); MMH(FA, BS, 2, NH, 3);                              \
    MMH(FA, BS, 3, NH, 0); MMH(FA, BS, 3, NH, 1);                              \
    MMH(FA, BS, 3, NH, 2); MMH(FA, BS, 3, NH, 3);                              \
    __builtin_amdgcn_s_setprio(0);                                             \
} while (0)

__global__ __launch_bounds__(256, 2)
void gemm_i8(const signed char* __restrict__ A8t,  // X8 fragment-linear (8 MB)
             const signed char* __restrict__ B8t,  // W8 fragment-linear (45 MB)
             const float* __restrict__ dxv,
             const float* __restrict__ sxv,
             const float* __restrict__ S,
             const float* __restrict__ Z,
             const float* __restrict__ Bias,
             float* __restrict__ O)
{
    const int tid  = threadIdx.x;
    const int lane = tid & 63;
    const int wid  = tid >> 6;
    const int wr   = wid >> 1;   // 0..1  (M half, 64 rows)
    const int wc   = wid & 1;    // 0..1  (N half, 128 cols)
    const int fr   = lane & 15;
    const int fg   = lane >> 4;

    const int bid  = blockIdx.x;   // 0..511
    const int xcd  = bid & 7;
    const int j    = bid >> 3;     // 0..63
    const int k0   = (j < 42) ? j : 42 + 2 * (j - 42);
    const int ncnt = (j < 42) ? 1 : 2;

    #pragma unroll 1
    for (int tt = 0; tt < ncnt; ++tt) {
        const int k = k0 + tt;
        int col, by;
        if (k < 80) { col = 5 * xcd + (k >> 4); by = k & 15; }
        else        { const int e = k - 80; col = 40 + (e >> 1); by = 2 * xcd + (e & 1); }
        const long bm = (long)by * 128;
        const long bn = (long)col * 256;

        const char* gAt = (const char*)A8t
                        + (((size_t)(by * 8 + wr * 4)) * 64 + lane) * 16;
        const char* gBt = (const char*)B8t
                        + (((size_t)(col * 16 + wc * 8)) * 64 + lane) * 16;

        i32x4 acc[4][8] = {};
        i32x4 pa0, pa1, pa2, pa3, qa0, qa1, qa2, qa3;      // A ping-pong
        i32x4 b00, b01, b02, b03;                          // B half-set 0
        i32x4 b10, b11, b12, b13;                          // B half-set 1
        i32x4 b20, b21, b22, b23;                          // B half-set 2
        i32x4 b30, b31, b32, b33;                          // B half-set 3

        // prologue: B halves H0,H1,H2 -> b0,b1,b2; A tiles 0,1 -> pa,qa
        LOAD_BH(b0, 0);
        LOAD_BH(b1, 1);
        LOAD_BH(b2, 2);
        LOAD_A4(pa, 0);
        LOAD_A4(qa, 1);

        #pragma unroll 1
        for (int i = 0; i < 31; ++i) {
            const int h = 4 * i;
            LOAD_BH(b3, h + 3); MFMA16H(pa, b0, 0);
            LOAD_BH(b0, h + 4); MFMA16H(pa, b1, 1); LOAD_A4(pa, 2 * i + 2);
            LOAD_BH(b1, h + 5); MFMA16H(qa, b2, 0);
            LOAD_BH(b2, h + 6); MFMA16H(qa, b3, 1); LOAD_A4(qa, 2 * i + 3);
        }
        // tail: half-steps 124..127 (tiles 62,63)
        LOAD_BH(b3, 127); MFMA16H(pa, b0, 0);
        MFMA16H(pa, b1, 1);
        MFMA16H(qa, b2, 0);
        MFMA16H(qa, b3, 1);

        // epilogue: y = s*dx*(acc + (128-zp)*sx) + bias
        // C/D: col = lane&15, row = (lane>>4)*4 + reg
        float dxa[16], sxa[16];
        #pragma unroll
        for (int m = 0; m < 4; ++m)
            #pragma unroll
            for (int r = 0; r < 4; ++r) {
                const int row = (int)bm + wr * 64 + m * 16 + (fg << 2) + r;
                dxa[m * 4 + r] = dxv[row];
                sxa[m * 4 + r] = sxv[row];
            }
        #pragma unroll
        for (int n = 0; n < 8; ++n) {
            const long ocol = bn + wc * 128 + n * 16 + fr;
            const float s  = S[ocol];
            const float f  = 128.f - Z[ocol];
            const float bi = Bias[ocol];
            #pragma unroll
            for (int m = 0; m < 4; ++m) {
                const long row0 = bm + wr * 64 + m * 16 + (fg << 2);
                #pragma unroll
                for (int r = 0; r < 4; ++r) {
                    const float g = (float)acc[m][n][r] + f * sxa[m * 4 + r];
                    O[(size_t)(row0 + r) * N_OUT + ocol] = s * dxa[m * 4 + r] * g + bi;
                }
            }
        }
    }
}

// ---------------- fallback (fused bf16) if ws too small ----------------
__global__ __launch_bounds__(256)
void qlinear_fused(const float* __restrict__ X,
                   const int*   __restrict__ Q,
                   const float* __restrict__ S,
                   const float* __restrict__ Z,
                   const float* __restrict__ Bias,
                   float* __restrict__ O)
{
    __shared__ bf16_t As[128][32];
    __shared__ bf16_t Bs[128][32];
    const int tid = threadIdx.x, lane = tid & 63, wid = tid >> 6;
    const int wr = wid >> 1, wc = wid & 1, fr = lane & 15, fg = lane >> 4;
    const int bm = blockIdx.y * 128, bn = blockIdx.x * 128;
    const int srow = tid >> 1, scol = (tid & 1) << 4;
    const float s_n = S[bn + srow];
    const float zs_n = Z[bn + srow] * s_n;
    const float* xptr = X + (size_t)(bm + srow) * K_IN + scol;
    const int*   qptr = Q + (size_t)(bn + srow) * K_IN + scol;
    f32x4 acc[4][4] = {};
    for (int k0 = 0; k0 < K_IN; k0 += 32) {
        float a[16]; int qi[16];
        { const float4* s4 = (const float4*)(xptr + k0);
          *(float4*)(a+0)=s4[0]; *(float4*)(a+4)=s4[1]; *(float4*)(a+8)=s4[2]; *(float4*)(a+12)=s4[3]; }
        { const int4* s4 = (const int4*)(qptr + k0);
          *(int4*)(qi+0)=s4[0]; *(int4*)(qi+4)=s4[1]; *(int4*)(qi+8)=s4[2]; *(int4*)(qi+12)=s4[3]; }
        float b[16];
        #pragma unroll
        for (int j = 0; j < 16; ++j) b[j] = (float)qi[j] * s_n - zs_n;
        bf16x8 pa0, pa1, pb0, pb1;
        #pragma unroll
        for (int j = 0; j < 8; ++j) {
            pa0[j]=(bf16_t)a[j]; pa1[j]=(bf16_t)a[j+8];
            pb0[j]=(bf16_t)b[j]; pb1[j]=(bf16_t)b[j+8];
        }
        *(bf16x8*)&As[srow][scol]   = pa0; *(bf16x8*)&As[srow][scol+8] = pa1;
        *(bf16x8*)&Bs[srow][scol]   = pb0; *(bf16x8*)&Bs[srow][scol+8] = pb1;
        __syncthreads();
        bf16x8 af[4], bfv[4];
        #pragma unroll
        for (int m = 0; m < 4; ++m) af[m] = *(const bf16x8*)&As[wr*64+m*16+fr][fg*8];
        #pragma unroll
        for (int n = 0; n < 4; ++n) bfv[n] = *(const bf16x8*)&Bs[wc*64+n*16+fr][fg*8];
        #pragma unroll
        for (int m = 0; m < 4; ++m)
            #pragma unroll
            for (int n = 0; n < 4; ++n)
                acc[m][n] = __builtin_amdgcn_mfma_f32_16x16x32_bf16(af[m], bfv[n], acc[m][n], 0,0,0);
        __syncthreads();
    }
    #pragma unroll
    for (int n = 0; n < 4; ++n) {
        const int col = bn + wc*64 + n*16 + fr;
        const float bv = Bias[col];
        #pragma unroll
        for (int m = 0; m < 4; ++m) {
            const int row0 = bm + wr*64 + m*16 + fg*4;
            #pragma unroll
            for (int r = 0; r < 4; ++r)
                O[(size_t)(row0 + r) * N_OUT + col] = acc[m][n][r] + bv;
        }
    }
}

extern "C" void kernel_launch(void* const* d_in, const int* in_sizes, int n_in,
                              void* d_out, int out_size, void* d_ws, size_t ws_size,
                              hipStream_t stream) {
    const float* X    = (const float*)d_in[0];
    const int*   Q    = (const int*)d_in[1];
    const float* S    = (const float*)d_in[2];
    const float* Z    = (const float*)d_in[3];
    const float* Bias = (const float*)d_in[4];
    float* O = (float*)d_out;

    const size_t wbytes = (size_t)N_OUT * K_IN;          // 45,088,768
    const size_t xbytes = (size_t)M_TOK * K_IN;          //  8,388,608
    const size_t need   = wbytes + xbytes + 2 * M_TOK * sizeof(float) + 256;

    if (ws_size >= need) {
        signed char* W8t = (signed char*)d_ws;
        signed char* X8t = (signed char*)d_ws + wbytes;
        float* dxv = (float*)((char*)d_ws + wbytes + xbytes);
        float* sxv = dxv + M_TOK;
        prep<<<dim3(N16 + M_TOK), 256, 0, stream>>>(Q, X, W8t, X8t, dxv, sxv);
        gemm_i8<<<dim3(512), 256, 0, stream>>>(X8t, W8t, dxv, sxv, S, Z, Bias, O);
    } else {
        dim3 grid(N_OUT / 128, M_TOK / 128);
        qlinear_fused<<<grid, 256, 0, stream>>>(X, Q, S, Z, Bias, O);
    }
}

// Round 21
// 166.462 us; speedup vs baseline: 1.0625x; 1.0625x over previous
//
#include <hip/hip_runtime.h>
#include <hip/hip_bf16.h>
#include <stdint.h>

typedef __bf16 bf16_t;
typedef bf16_t bf16x8 __attribute__((ext_vector_type(8)));
typedef float  f32x4  __attribute__((ext_vector_type(4)));
typedef int    i32x4  __attribute__((ext_vector_type(4)));

#define M_TOK 2048
#define N_OUT 11008
#define K_IN  4096
#define N16   (N_OUT / 16)   // 688
#define NTILE 688            // 16 by (128 rows) x 43 col (256 cols)

// ---------- merged pre-pass: W repack (blocks 0..687) + X quant (688..2735) --
// W8t: B-frag (kt, n16) = 1 KB at ((kt*688 + n16)*64 + lane)*16.
// X8t: A-frag (kt, m16) = 1 KB at ((kt*128 + m16)*64 + lane)*16.
__global__ __launch_bounds__(256)
void prep(const int* __restrict__ Q, const float* __restrict__ X,
          signed char* __restrict__ W8t, signed char* __restrict__ X8t,
          float* __restrict__ dxv, float* __restrict__ sxv)
{
    __shared__ float wmax[4];
    __shared__ int   wsum[4];
    const int tid = threadIdx.x;

    if (blockIdx.x < N16) {
        const int n16 = blockIdx.x;
        const int fr  = tid & 15;
        const int fg  = (tid >> 4) & 3;
        const int w   = tid >> 6;
        const int* qrow = Q + (size_t)(n16 * 16 + fr) * K_IN + fg * 16;
        signed char* wout = W8t + ((size_t)n16 * 64 + (tid & 63)) * 16;
        #pragma unroll 4
        for (int kt2 = 0; kt2 < 16; ++kt2) {
            const int kt = kt2 * 4 + w;
            const int4* q4 = (const int4*)(qrow + kt * 64);
            unsigned int pk[4];
            #pragma unroll
            for (int j = 0; j < 4; ++j) {
                const int4 q = q4[j];
                pk[j] =  (unsigned int)((q.x - 128) & 255)
                      | ((unsigned int)((q.y - 128) & 255) << 8)
                      | ((unsigned int)((q.z - 128) & 255) << 16)
                      | ((unsigned int)((q.w - 128) & 255) << 24);
            }
            *(int4*)(wout + (size_t)kt * (N16 * 1024)) = *(const int4*)pk;
        }
        return;
    }

    const int row = blockIdx.x - N16;
    const float* xr = X + (size_t)row * K_IN + tid * 16;
    float v[16];
    #pragma unroll
    for (int j = 0; j < 4; ++j)
        *(float4*)(v + j * 4) = ((const float4*)xr)[j];

    float amax = 0.f;
    #pragma unroll
    for (int j = 0; j < 16; ++j) amax = fmaxf(amax, fabsf(v[j]));
    #pragma unroll
    for (int m = 1; m < 64; m <<= 1)
        amax = fmaxf(amax, __shfl_xor(amax, m));
    const int wv = tid >> 6;
    if ((tid & 63) == 0) wmax[wv] = amax;
    __syncthreads();
    amax = fmaxf(fmaxf(wmax[0], wmax[1]), fmaxf(wmax[2], wmax[3]));
    amax = fmaxf(amax, 1e-20f);
    const float inv = 127.f / amax;

    int sum = 0;
    unsigned int pk[4];
    #pragma unroll
    for (int j = 0; j < 4; ++j) {
        unsigned int p = 0;
        #pragma unroll
        for (int i = 0; i < 4; ++i) {
            int xi = (int)__builtin_rintf(v[j * 4 + i] * inv);
            xi = max(-127, min(127, xi));
            sum += xi;
            p |= ((unsigned int)(xi & 255)) << (8 * i);
        }
        pk[j] = p;
    }
    const size_t toff = (((size_t)(tid >> 2) * 128 + (row >> 4)) * 64
                         + (size_t)((tid & 3) * 16 + (row & 15))) * 16;
    *(int4*)(X8t + toff) = *(const int4*)pk;

    #pragma unroll
    for (int m = 1; m < 64; m <<= 1) sum += __shfl_xor(sum, m);
    if ((tid & 63) == 0) wsum[wv] = sum;
    __syncthreads();
    if (tid == 0) {
        dxv[row] = amax * (1.f / 127.f);
        sxv[row] = (float)(wsum[0] + wsum[1] + wsum[2] + wsum[3]);
    }
}

// ---------------- main GEMM: i8 128x256, NO LDS (r18 = measured best) --------
// 4 waves (2M x 2N), per-wave 64x128 = 4x8 16x16 tiles; named P/Q frag
// ping-pong; setprio kept (r13 A/B: -22% without). XCD col-partition map
// (FETCH 123MB verified). Raw s_barrier every 4 iterations re-aligns waves.

#define LOAD_A4B4(DA, DB, KT) do {                                             \
    const char* ap_ = gAt + (size_t)(KT) * (128 * 1024);                       \
    DA##0 = *(const i32x4*)(ap_ + 0 * 1024);                                   \
    DA##1 = *(const i32x4*)(ap_ + 1 * 1024);                                   \
    DA##2 = *(const i32x4*)(ap_ + 2 * 1024);                                   \
    DA##3 = *(const i32x4*)(ap_ + 3 * 1024);                                   \
    const char* bp_ = gBt + (size_t)(KT) * (N16 * 1024);                       \
    DB##0 = *(const i32x4*)(bp_ + 0 * 1024);                                   \
    DB##1 = *(const i32x4*)(bp_ + 1 * 1024);                                   \
    DB##2 = *(const i32x4*)(bp_ + 2 * 1024);                                   \
    DB##3 = *(const i32x4*)(bp_ + 3 * 1024);                                   \
} while (0)

#define LOAD_B4(DB, KT) do {                                                   \
    const char* bp_ = gBt + (size_t)(KT) * (N16 * 1024);                       \
    DB##4 = *(const i32x4*)(bp_ + 4 * 1024);                                   \
    DB##5 = *(const i32x4*)(bp_ + 5 * 1024);                                   \
    DB##6 = *(const i32x4*)(bp_ + 6 * 1024);                                   \
    DB##7 = *(const i32x4*)(bp_ + 7 * 1024);                                   \
} while (0)

#define MMQ(FA, FB, MQ, NQ)                                                    \
    acc[MQ][NQ] = __builtin_amdgcn_mfma_i32_16x16x64_i8(FA##MQ, FB##NQ, acc[MQ][NQ], 0, 0, 0)

#define MFMA16_LO(FA, FB) do {                                                 \
    __builtin_amdgcn_s_setprio(1);                                             \
    MMQ(FA, FB, 0, 0); MMQ(FA, FB, 0, 1); MMQ(FA, FB, 0, 2); MMQ(FA, FB, 0, 3);\
    MMQ(FA, FB, 0, 4); MMQ(FA, FB, 0, 5); MMQ(FA, FB, 0, 6); MMQ(FA, FB, 0, 7);\
    MMQ(FA, FB, 1, 0); MMQ(FA, FB, 1, 1); MMQ(FA, FB, 1, 2); MMQ(FA, FB, 1, 3);\
    MMQ(FA, FB, 1, 4); MMQ(FA, FB, 1, 5); MMQ(FA, FB, 1, 6); MMQ(FA, FB, 1, 7);\
    __builtin_amdgcn_s_setprio(0);                                             \
} while (0)

#define MFMA16_HI(FA, FB) do {                                                 \
    __builtin_amdgcn_s_setprio(1);                                             \
    MMQ(FA, FB, 2, 0); MMQ(FA, FB, 2, 1); MMQ(FA, FB, 2, 2); MMQ(FA, FB, 2, 3);\
    MMQ(FA, FB, 2, 4); MMQ(FA, FB, 2, 5); MMQ(FA, FB, 2, 6); MMQ(FA, FB, 2, 7);\
    MMQ(FA, FB, 3, 0); MMQ(FA, FB, 3, 1); MMQ(FA, FB, 3, 2); MMQ(FA, FB, 3, 3);\
    MMQ(FA, FB, 3, 4); MMQ(FA, FB, 3, 5); MMQ(FA, FB, 3, 6); MMQ(FA, FB, 3, 7);\
    __builtin_amdgcn_s_setprio(0);                                             \
} while (0)

#define REGION21(CA, CB, NA, NB, KTN) do {                                     \
    LOAD_A4B4(NA, NB, KTN);                                                    \
    MFMA16_LO(CA, CB);                                                         \
    LOAD_B4(NB, KTN);                                                          \
    MFMA16_HI(CA, CB);                                                         \
} while (0)

__global__ __launch_bounds__(256, 2)
void gemm_i8(const signed char* __restrict__ A8t,  // X8 fragment-linear (8 MB)
             const signed char* __restrict__ B8t,  // W8 fragment-linear (45 MB)
             const float* __restrict__ dxv,
             const float* __restrict__ sxv,
             const float* __restrict__ S,
             const float* __restrict__ Z,
             const float* __restrict__ Bias,
             float* __restrict__ O)
{
    const int tid  = threadIdx.x;
    const int lane = tid & 63;
    const int wid  = tid >> 6;
    const int wr   = wid >> 1;   // 0..1  (M half, 64 rows)
    const int wc   = wid & 1;    // 0..1  (N half, 128 cols)
    const int fr   = lane & 15;
    const int fg   = lane >> 4;

    // XCD col-partition (r14-verified): xcd owns cols 5x..5x+4 x 16 by + spill
    const int bid = blockIdx.x;
    const int xcd = bid & 7;
    const int k   = bid >> 3;           // 0..85
    int col, by;
    if (k < 80) { col = 5 * xcd + (k >> 4); by = k & 15; }
    else        { const int e = k - 80; col = 40 + (e >> 1); by = 2 * xcd + (e & 1); }
    const long bm = (long)by * 128;
    const long bn = (long)col * 256;

    const char* gAt = (const char*)A8t
                    + (((size_t)(by * 8 + wr * 4)) * 64 + lane) * 16;
    const char* gBt = (const char*)B8t
                    + (((size_t)(col * 16 + wc * 8)) * 64 + lane) * 16;

    i32x4 acc[4][8] = {};
    i32x4 pa0, pa1, pa2, pa3, pb0, pb1, pb2, pb3, pb4, pb5, pb6, pb7;
    i32x4 qa0, qa1, qa2, qa3, qb0, qb1, qb2, qb3, qb4, qb5, qb6, qb7;

    // prologue: load tile 0 into P
    LOAD_A4B4(pa, pb, 0);
    LOAD_B4(pb, 0);

    #pragma unroll 1
    for (int i = 0; i < 31; ++i) {
        if ((i & 3) == 0) __builtin_amdgcn_s_barrier();  // wave re-align
        REGION21(pa, pb, qa, qb, 2 * i + 1);   // MFMA P, prefetch Q
        REGION21(qa, qb, pa, pb, 2 * i + 2);   // MFMA Q, prefetch P
    }
    REGION21(pa, pb, qa, qb, 63);
    MFMA16_LO(qa, qb);
    MFMA16_HI(qa, qb);

    // epilogue: y = s*dx*(acc + (128-zp)*sx) + bias
    // C/D: col = lane&15, row = (lane>>4)*4 + reg (shape-determined, verified)
    float dxa[16], sxa[16];
    #pragma unroll
    for (int m = 0; m < 4; ++m)
        #pragma unroll
        for (int r = 0; r < 4; ++r) {
            const int row = (int)bm + wr * 64 + m * 16 + (fg << 2) + r;
            dxa[m * 4 + r] = dxv[row];
            sxa[m * 4 + r] = sxv[row];
        }
    #pragma unroll
    for (int n = 0; n < 8; ++n) {
        const long ocol = bn + wc * 128 + n * 16 + fr;
        const float s  = S[ocol];
        const float f  = 128.f - Z[ocol];
        const float bi = Bias[ocol];
        #pragma unroll
        for (int m = 0; m < 4; ++m) {
            const long row0 = bm + wr * 64 + m * 16 + (fg << 2);
            #pragma unroll
            for (int r = 0; r < 4; ++r) {
                const float g = (float)acc[m][n][r] + f * sxa[m * 4 + r];
                O[(size_t)(row0 + r) * N_OUT + ocol] = s * dxa[m * 4 + r] * g + bi;
            }
        }
    }
}

// ---------------- fallback (fused bf16) if ws too small ----------------
__global__ __launch_bounds__(256)
void qlinear_fused(const float* __restrict__ X,
                   const int*   __restrict__ Q,
                   const float* __restrict__ S,
                   const float* __restrict__ Z,
                   const float* __restrict__ Bias,
                   float* __restrict__ O)
{
    __shared__ bf16_t As[128][32];
    __shared__ bf16_t Bs[128][32];
    const int tid = threadIdx.x, lane = tid & 63, wid = tid >> 6;
    const int wr = wid >> 1, wc = wid & 1, fr = lane & 15, fg = lane >> 4;
    const int bm = blockIdx.y * 128, bn = blockIdx.x * 128;
    const int srow = tid >> 1, scol = (tid & 1) << 4;
    const float s_n = S[bn + srow];
    const float zs_n = Z[bn + srow] * s_n;
    const float* xptr = X + (size_t)(bm + srow) * K_IN + scol;
    const int*   qptr = Q + (size_t)(bn + srow) * K_IN + scol;
    f32x4 acc[4][4] = {};
    for (int k0 = 0; k0 < K_IN; k0 += 32) {
        float a[16]; int qi[16];
        { const float4* s4 = (const float4*)(xptr + k0);
          *(float4*)(a+0)=s4[0]; *(float4*)(a+4)=s4[1]; *(float4*)(a+8)=s4[2]; *(float4*)(a+12)=s4[3]; }
        { const int4* s4 = (const int4*)(qptr + k0);
          *(int4*)(qi+0)=s4[0]; *(int4*)(qi+4)=s4[1]; *(int4*)(qi+8)=s4[2]; *(int4*)(qi+12)=s4[3]; }
        float b[16];
        #pragma unroll
        for (int j = 0; j < 16; ++j) b[j] = (float)qi[j] * s_n - zs_n;
        bf16x8 pa0, pa1, pb0, pb1;
        #pragma unroll
        for (int j = 0; j < 8; ++j) {
            pa0[j]=(bf16_t)a[j]; pa1[j]=(bf16_t)a[j+8];
            pb0[j]=(bf16_t)b[j]; pb1[j]=(bf16_t)b[j+8];
        }
        *(bf16x8*)&As[srow][scol]   = pa0; *(bf16x8*)&As[srow][scol+8] = pa1;
        *(bf16x8*)&Bs[srow][scol]   = pb0; *(bf16x8*)&Bs[srow][scol+8] = pb1;
        __syncthreads();
        bf16x8 af[4], bfv[4];
        #pragma unroll
        for (int m = 0; m < 4; ++m) af[m] = *(const bf16x8*)&As[wr*64+m*16+fr][fg*8];
        #pragma unroll
        for (int n = 0; n < 4; ++n) bfv[n] = *(const bf16x8*)&Bs[wc*64+n*16+fr][fg*8];
        #pragma unroll
        for (int m = 0; m < 4; ++m)
            #pragma unroll
            for (int n = 0; n < 4; ++n)
                acc[m][n] = __builtin_amdgcn_mfma_f32_16x16x32_bf16(af[m], bfv[n], acc[m][n], 0,0,0);
        __syncthreads();
    }
    #pragma unroll
    for (int n = 0; n < 4; ++n) {
        const int col = bn + wc*64 + n*16 + fr;
        const float bv = Bias[col];
        #pragma unroll
        for (int m = 0; m < 4; ++m) {
            const int row0 = bm + wr*64 + m*16 + fg*4;
            #pragma unroll
            for (int r = 0; r < 4; ++r)
                O[(size_t)(row0 + r) * N_OUT + col] = acc[m][n][r] + bv;
        }
    }
}

extern "C" void kernel_launch(void* const* d_in, const int* in_sizes, int n_in,
                              void* d_out, int out_size, void* d_ws, size_t ws_size,
                              hipStream_t stream) {
    const float* X    = (const float*)d_in[0];
    const int*   Q    = (const int*)d_in[1];
    const float* S    = (const float*)d_in[2];
    const float* Z    = (const float*)d_in[3];
    const float* Bias = (const float*)d_in[4];
    float* O = (float*)d_out;

    const size_t wbytes = (size_t)N_OUT * K_IN;          // 45,088,768
    const size_t xbytes = (size_t)M_TOK * K_IN;          //  8,388,608
    const size_t need   = wbytes + xbytes + 2 * M_TOK * sizeof(float) + 256;

    if (ws_size >= need) {
        signed char* W8t = (signed char*)d_ws;
        signed char* X8t = (signed char*)d_ws + wbytes;
        float* dxv = (float*)((char*)d_ws + wbytes + xbytes);
        float* sxv = dxv + M_TOK;
        prep<<<dim3(N16 + M_TOK), 256, 0, stream>>>(Q, X, W8t, X8t, dxv, sxv);
        gemm_i8<<<dim3(NTILE), 256, 0, stream>>>(X8t, W8t, dxv, sxv, S, Z, Bias, O);
    } else {
        dim3 grid(N_OUT / 128, M_TOK / 128);
        qlinear_fused<<<grid, 256, 0, stream>>>(X, Q, S, Z, Bias, O);
    }
}